// Round 17
// baseline (93.545 us; speedup 1.0000x reference)
//
#include <hip/hip_runtime.h>
#include <cstdint>
#include <cstddef>

typedef __bf16 bf16;
typedef bf16 bf16x4 __attribute__((ext_vector_type(4)));
typedef bf16 bf16x8 __attribute__((ext_vector_type(8)));
typedef float f32x4 __attribute__((ext_vector_type(4)));

#define S_LEN 2048
#define DIM   1024
#define NHEAD 16
#define HDIM  64

__device__ __forceinline__ f32x4 mfma16(bf16x8 a, bf16x8 b, f32x4 c) {
    return __builtin_amdgcn_mfma_f32_16x16x32_bf16(a, b, c, 0, 0, 0);
}

__device__ __forceinline__ float exp2fast(float x) {
    return __builtin_amdgcn_exp2f(x);   // v_exp_f32: 2^x
}

__device__ __forceinline__ void gload_lds16(const bf16* g, bf16* l) {
    __builtin_amdgcn_global_load_lds(
        (const __attribute__((address_space(1))) unsigned*)g,
        (__attribute__((address_space(3))) unsigned*)l, 16, 0, 0);
}

// ================ prep kernel: x convert + RoPE table + 4x weight transpose, ONE dispatch ================
__global__ __launch_bounds__(256) void prep_kernel(const float* __restrict__ x,
                                                   const float* __restrict__ cosp,
                                                   const float* __restrict__ sinp,
                                                   const float* __restrict__ Wq, const float* __restrict__ Wk,
                                                   const float* __restrict__ Wv, const float* __restrict__ Wo,
                                                   bf16* __restrict__ xb, float4* __restrict__ tab,
                                                   bf16* __restrict__ WqT, bf16* __restrict__ WkT,
                                                   bf16* __restrict__ WvT, bf16* __restrict__ WoT) {
    __shared__ bf16 tile[64][72];
    int blk = blockIdx.x;
    int t = threadIdx.x;
    if (blk < 4096) {
        int i = blk * 256 + t;
        float4 v = ((const float4*)x)[i];
        bf16x4 o = { (bf16)v.x, (bf16)v.y, (bf16)v.z, (bf16)v.w };
        ((bf16x4*)xb)[i] = o;
    } else if (blk < 4608) {
        int i = (blk - 4096) * 256 + t;       // [0, 131072)
        int bs = i >> 5, hd1 = i & 31;
        size_t cb = (size_t)bs * HDIM + hd1;
        tab[i] = make_float4(cosp[cb], sinp[cb], cosp[cb + 32], sinp[cb + 32]);
    } else {
        int blk2 = blk - 4608;                // [0, 1024)
        int z = blk2 >> 8, rem = blk2 & 255;
        int bx = rem & 15, by = rem >> 4;
        const float* W; bf16* WT;
        if      (z == 0) { W = Wq; WT = WqT; }
        else if (z == 1) { W = Wk; WT = WkT; }
        else if (z == 2) { W = Wv; WT = WvT; }
        else             { W = Wo; WT = WoT; }
        int k0 = bx * 64, n0 = by * 64;
#pragma unroll
        for (int p = 0; p < 4; ++p) {
            int task = p * 256 + t;
            int ki = task >> 4, nj = (task & 15) * 4;
            float4 v = *(const float4*)(W + (size_t)(k0 + ki) * DIM + n0 + nj);
            tile[ki][nj + 0] = (bf16)v.x; tile[ki][nj + 1] = (bf16)v.y;
            tile[ki][nj + 2] = (bf16)v.z; tile[ki][nj + 3] = (bf16)v.w;
        }
        __syncthreads();
#pragma unroll
        for (int p = 0; p < 4; ++p) {
            int task = p * 256 + t;
            int ni = task >> 4, kj = (task & 15) * 4;
            bf16x4 o = { tile[kj + 0][ni], tile[kj + 1][ni], tile[kj + 2][ni], tile[kj + 3][ni] };
            *(bf16x4*)(WT + (size_t)(n0 + ni) * DIM + k0 + kj) = o;
        }
    }
}

// ---------------- 128x128 GEMM main loop, ring-3, counted vmcnt (FINAL) ----------------
__device__ __forceinline__ void stage_tile(const bf16* __restrict__ A, const bf16* __restrict__ BT,
                                           int m0, int n0, int k0,
                                           bf16* sA, bf16* sB, int w, int lane) {
#pragma unroll
    for (int p = 0; p < 2; ++p) {
        int c = p * 256 + w * 64 + lane;
        const bf16* ga = A + (size_t)(m0 + (c >> 2)) * DIM + k0 + (c & 3) * 8;
        gload_lds16(ga, sA + (p * 256 + w * 64) * 8);
        const bf16* gb = BT + (size_t)(n0 + (c >> 2)) * DIM + k0 + (c & 3) * 8;
        gload_lds16(gb, sB + (p * 256 + w * 64) * 8);
    }
}

__device__ __forceinline__ void gemm_main(const bf16* __restrict__ A, const bf16* __restrict__ BT,
                                          int m0, int n0, f32x4 acc[4][4]) {
    __shared__ bf16 sA[3][128 * 32];
    __shared__ bf16 sB[3][128 * 32];
    int t = threadIdx.x;
    int lane = t & 63, w = t >> 6;
    int wr = w >> 1, wc = w & 1;
    int lc = lane & 15, lr = lane >> 4;
    const int NSTEP = DIM / 32;           // 32

    stage_tile(A, BT, m0, n0, 0,  sA[0], sB[0], w, lane);
    stage_tile(A, BT, m0, n0, 32, sA[1], sB[1], w, lane);

    int rs = 0, ss = 2;
    for (int kt = 0; kt < NSTEP; ++kt) {
        if (kt < NSTEP - 1) asm volatile("s_waitcnt vmcnt(4)" ::: "memory");
        else                asm volatile("s_waitcnt vmcnt(0)" ::: "memory");
        __builtin_amdgcn_s_barrier();
        asm volatile("" ::: "memory");
        if (kt < NSTEP - 2)
            stage_tile(A, BT, m0, n0, (kt + 2) * 32, sA[ss], sB[ss], w, lane);

        const bf16* pa = sA[rs] + (wr * 64 + lc) * 32 + lr * 8;
        const bf16* pb = sB[rs] + (wc * 64 + lc) * 32 + lr * 8;
        bf16x8 af[4], bfr[4];
#pragma unroll
        for (int m = 0; m < 4; ++m) af[m] = *(const bf16x8*)(pa + m * 16 * 32);
#pragma unroll
        for (int n = 0; n < 4; ++n) bfr[n] = *(const bf16x8*)(pb + n * 16 * 32);
#pragma unroll
        for (int m = 0; m < 4; ++m)
#pragma unroll
            for (int n = 0; n < 4; ++n)
                acc[m][n] = mfma16(af[m], bfr[n], acc[m][n]);
        rs = (rs == 2) ? 0 : rs + 1;
        ss = (ss == 2) ? 0 : ss + 1;
    }
}

// ---------------- fused QKV GEMM + bias + RoPE (table) + head relayout (FINAL) ----------------
__global__ __launch_bounds__(256, 3) void gemm_qkv_kernel(const bf16* __restrict__ xb,
                                                          const bf16* __restrict__ WqT, const bf16* __restrict__ WkT,
                                                          const bf16* __restrict__ WvT,
                                                          const float* __restrict__ bq, const float* __restrict__ bv,
                                                          const float4* __restrict__ tab,
                                                          bf16* __restrict__ qT, bf16* __restrict__ kT,
                                                          bf16* __restrict__ vT) {
    int z = blockIdx.z;
    const bf16* BT = (z == 0) ? WqT : (z == 1) ? WkT : WvT;
    int m0 = blockIdx.x * 128, n0 = blockIdx.y * 128;
    f32x4 acc[4][4] = {};
    gemm_main(xb, BT, m0, n0, acc);

    int t = threadIdx.x;
    int lane = t & 63, w = t >> 6;
    int wr = w >> 1, wc = w & 1;
    int lc = lane & 15, lr = lane >> 4;
    int row0 = m0 + wr * 64 + lr * 4;       // bs base
    int h = (n0 >> 6) + wc;                  // head

    if (z < 2) {
        bf16* qkT = (z == 0) ? qT : kT;
#pragma unroll
        for (int nf = 0; nf < 2; ++nf) {
            int hd1 = lc + nf * 16;          // 0..31
            int c1i = h * HDIM + hd1;
            float b1 = (z == 0) ? bq[c1i] : 0.0f;
            float b2 = (z == 0) ? bq[c1i + 32] : 0.0f;
#pragma unroll
            for (int mf = 0; mf < 4; ++mf) {
#pragma unroll
                for (int r = 0; r < 4; ++r) {
                    int bs = row0 + mf * 16 + r;
                    float4 cs = tab[bs * 32 + hd1];      // (c1, s1, c2, s2)
                    float v1 = acc[mf][nf][r] + b1;
                    float v2 = acc[mf][nf + 2][r] + b2;
                    int b = bs >> 11, s = bs & (S_LEN - 1);
                    size_t o = ((size_t)(b * NHEAD + h) * S_LEN + s) * HDIM;
                    qkT[o + hd1]      = (bf16)(v1 * cs.x - v2 * cs.y);
                    qkT[o + hd1 + 32] = (bf16)(v2 * cs.z + v1 * cs.w);
                }
            }
        }
    } else {
#pragma unroll
        for (int nf = 0; nf < 4; ++nf) {
            int hd = lc + nf * 16;
            float bvv = bv[h * HDIM + hd];
#pragma unroll
            for (int mf = 0; mf < 4; ++mf) {
                bf16x4 o;
#pragma unroll
                for (int r = 0; r < 4; ++r) o[r] = (bf16)(acc[mf][nf][r] + bvv);
                int bs = row0 + mf * 16;
                int b = bs >> 11, s = bs & (S_LEN - 1);
                *(bf16x4*)(vT + ((size_t)((b * NHEAD + h) * HDIM + hd)) * S_LEN + s) = o;
            }
        }
    }
}

// ---------------- out GEMM: 128x64 tile, 2-wave blocks, ring-3, vmcnt(6) (FINAL) ----------------
__device__ __forceinline__ void stage_out(const bf16* __restrict__ A, const bf16* __restrict__ BT,
                                          int m0, int n0, int k0,
                                          bf16* sA, bf16* sB, int w, int t) {
#pragma unroll
    for (int i = 0; i < 4; ++i) {
        int c = i * 128 + t;
        const bf16* ga = A + (size_t)(m0 + (c >> 2)) * DIM + k0 + (c & 3) * 8;
        gload_lds16(ga, sA + (i * 128 + w * 64) * 8);
    }
#pragma unroll
    for (int i = 0; i < 2; ++i) {
        int c = i * 128 + t;
        const bf16* gb = BT + (size_t)(n0 + (c >> 2)) * DIM + k0 + (c & 3) * 8;
        gload_lds16(gb, sB + (i * 128 + w * 64) * 8);
    }
}

__global__ __launch_bounds__(128, 2) void gemm_out_kernel(const bf16* __restrict__ ctx, const bf16* __restrict__ WoT,
                                                          const float* __restrict__ bo, float* __restrict__ out) {
    __shared__ bf16 sA[3][128 * 32];
    __shared__ bf16 sB[3][64 * 32];
    int bid = blockIdx.x + 32 * blockIdx.y;          // 512 blocks
    int wg  = (bid & 7) * 64 + (bid >> 3);           // XCD-bijective (512 % 8 == 0)
    int bx = wg & 31, by = wg >> 5;
    int m0 = bx * 128, n0 = by * 64;
    int t = threadIdx.x, lane = t & 63, w = t >> 6;
    int lc = lane & 15, lr = lane >> 4;
    const int NSTEP = DIM / 32;

    f32x4 acc[4][4] = {};
    stage_out(ctx, WoT, m0, n0, 0,  sA[0], sB[0], w, t);
    stage_out(ctx, WoT, m0, n0, 32, sA[1], sB[1], w, t);

    int rs = 0, ss = 2;
    for (int kt = 0; kt < NSTEP; ++kt) {
        if (kt < NSTEP - 1) asm volatile("s_waitcnt vmcnt(6)" ::: "memory");
        else                asm volatile("s_waitcnt vmcnt(0)" ::: "memory");
        __builtin_amdgcn_s_barrier();
        asm volatile("" ::: "memory");
        if (kt < NSTEP - 2)
            stage_out(ctx, WoT, m0, n0, (kt + 2) * 32, sA[ss], sB[ss], w, t);

        const bf16* pa = sA[rs] + (w * 64 + lc) * 32 + lr * 8;
        const bf16* pb = sB[rs] + lc * 32 + lr * 8;
        bf16x8 af[4], bfr[4];
#pragma unroll
        for (int m = 0; m < 4; ++m) af[m] = *(const bf16x8*)(pa + m * 16 * 32);
#pragma unroll
        for (int n = 0; n < 4; ++n) bfr[n] = *(const bf16x8*)(pb + n * 16 * 32);
#pragma unroll
        for (int m = 0; m < 4; ++m)
#pragma unroll
            for (int n = 0; n < 4; ++n)
                acc[m][n] = mfma16(af[m], bfr[n], acc[m][n]);
        rs = (rs == 2) ? 0 : rs + 1;
        ss = (ss == 2) ? 0 : ss + 1;
    }

    int row0 = m0 + w * 64 + lr * 4;
#pragma unroll
    for (int nf = 0; nf < 4; ++nf) {
        int col = n0 + lc + nf * 16;
        float bvv = bo[col];
#pragma unroll
        for (int mf = 0; mf < 4; ++mf)
#pragma unroll
            for (int r = 0; r < 4; ++r)
                out[(size_t)(row0 + mf * 16 + r) * DIM + col] = acc[mf][nf][r] + bvv;
    }
}

// ================ flash attention: R12 structure + interior-tile mask-skip + defer-max (T13, THR=0) ================
__global__ __launch_bounds__(256, 3) void attn_kernel(const bf16* __restrict__ qT, const bf16* __restrict__ kT,
                                                      const bf16* __restrict__ vT, bf16* __restrict__ ctx) {
    int bid = blockIdx.x + 16 * blockIdx.y;      // 512 blocks
    int xcd = bid & 7, idx = bid >> 3;           // XCD-bijective: 8 x 4bh x 16qb
    int bh = xcd * 4 + (idx >> 4);               // 4 heads per XCD (2MB KV < 4MB L2)
    int qb = idx & 15;
    int b = bh >> 4, h = bh & 15;
    int t = threadIdx.x, lane = t & 63, w = t >> 6;
    int lc = lane & 15, lr = lane >> 4;

    __shared__ bf16 sK[2][4096];                 // [slot][key(64)][d(64)] swizzled
    __shared__ bf16 sV[2][4096];                 // [slot][d(64)][key(64)] swizzled
    __shared__ bf16 sP[4][2048];                 // per-wave P buffer

    const bf16* Qb = qT + (size_t)bh * S_LEN * HDIM;
    const bf16* Kb = kT + (size_t)bh * S_LEN * HDIM;
    const bf16* Vb = vT + (size_t)bh * HDIM * S_LEN;

    const float SCL = 0.125f * 1.44269504089f;   // 1/sqrt(64) * log2(e)
    const int swz = (lc & 7) << 4;               // involution swizzle (bytes)
    char* sPw = (char*)sP[w];

    int q0 = qb * 128 + w * 32;
    int kt_lo_b = (qb >= 2) ? (qb * 128 - 256) >> 6 : 0;
    int kt_hi_b = (qb * 128 + 127) >> 6;
    int klo_w = (q0 >= 256) ? (q0 - 256) >> 6 : 0;
    int khi_w = (q0 + 31) >> 6;

    bf16x8 qf[2][2];
#pragma unroll
    for (int mf = 0; mf < 2; ++mf)
#pragma unroll
        for (int kk = 0; kk < 2; ++kk)
            qf[mf][kk] = *(const bf16x8*)(Qb + (size_t)(q0 + mf * 16 + lc) * HDIM + kk * 32 + lr * 8);

    f32x4 accO[2][4] = {};
    float mrun[2] = { -30000.0f, -30000.0f };
    float lrun[2] = { 0.0f, 0.0f };

#define STAGE_KV(kt_, s_) {                                                             \
        int kbase_ = (kt_) * 64;                                                        \
        _Pragma("unroll")                                                               \
        for (int p = 0; p < 2; ++p) {                                                   \
            int c = p * 256 + t;                                                        \
            int row = c >> 3, ch = c & 7;                                               \
            int colb = (ch * 16) ^ ((row & 7) << 4);                                    \
            bf16* dst = (bf16*)&sK[s_][0] + (p * 256 + (t & ~63)) * 8;                  \
            gload_lds16(Kb + (size_t)(kbase_ + row) * HDIM + (colb >> 1), dst);         \
            bf16* dsv = (bf16*)&sV[s_][0] + (p * 256 + (t & ~63)) * 8;                  \
            gload_lds16(Vb + (size_t)row * S_LEN + kbase_ + (colb >> 1), dsv);          \
        }                                                                               \
    }

    STAGE_KV(kt_lo_b, 0);
    if (kt_lo_b + 1 <= kt_hi_b) STAGE_KV(kt_lo_b + 1, 1);

    for (int kt = kt_lo_b; kt <= kt_hi_b; ++kt) {
        int s = (kt - kt_lo_b) & 1;
        if (kt < kt_hi_b) asm volatile("s_waitcnt vmcnt(4)" ::: "memory");
        else              asm volatile("s_waitcnt vmcnt(0)" ::: "memory");
        __builtin_amdgcn_s_barrier();
        asm volatile("" ::: "memory");

        if (kt >= klo_w && kt <= khi_w) {
            int kbase = kt * 64;
            const char* kb = (const char*)&sK[s][0];
            const char* vb = (const char*)&sV[s][0];

            f32x4 sacc[2][4] = {};
            __builtin_amdgcn_s_setprio(1);
#pragma unroll
            for (int nf = 0; nf < 4; ++nf) {
                int key = nf * 16 + lc;
#pragma unroll
                for (int kk = 0; kk < 2; ++kk) {
                    bf16x8 kf = *(const bf16x8*)(kb + key * 128 + ((kk * 64 + lr * 16) ^ swz));
                    sacc[0][nf] = mfma16(kf, qf[0][kk], sacc[0][nf]);
                    sacc[1][nf] = mfma16(kf, qf[1][kk], sacc[1][nf]);
                }
            }
            __builtin_amdgcn_s_setprio(0);
            // interior tile (fully in-window for ALL 32 queries of this wave): skip masking
            bool fullkeep = (kbase + 63 <= q0) && (kbase >= q0 - 225);
            if (fullkeep) {
#pragma unroll
                for (int mf = 0; mf < 2; ++mf)
#pragma unroll
                    for (int nf = 0; nf < 4; ++nf)
#pragma unroll
                        for (int r = 0; r < 4; ++r)
                            sacc[mf][nf][r] *= SCL;
            } else {
#pragma unroll
                for (int mf = 0; mf < 2; ++mf) {
                    int qi = q0 + mf * 16 + lc;
#pragma unroll
                    for (int nf = 0; nf < 4; ++nf)
#pragma unroll
                        for (int r = 0; r < 4; ++r) {
                            int ki = kbase + nf * 16 + lr * 4 + r;
                            bool keep = (ki <= qi) && (ki >= qi - 256);
                            sacc[mf][nf][r] = keep ? sacc[mf][nf][r] * SCL : -30000.0f;
                        }
                }
            }
            // online softmax per query-lane, with defer-max (THR=0: alpha==1 path is exact)
#pragma unroll
            for (int mf = 0; mf < 2; ++mf) {
                float mx = sacc[mf][0][0];
#pragma unroll
                for (int nf = 0; nf < 4; ++nf)
#pragma unroll
                    for (int r = 0; r < 4; ++r) mx = fmaxf(mx, sacc[mf][nf][r]);
                mx = fmaxf(mx, __shfl_xor(mx, 16));
                mx = fmaxf(mx, __shfl_xor(mx, 32));
                if (__any(mx > mrun[mf])) {
                    float mnew = fmaxf(mrun[mf], mx);
                    float alpha = exp2fast(mrun[mf] - mnew);
                    mrun[mf] = mnew;
                    float rsum = 0.0f;
#pragma unroll
                    for (int nf = 0; nf < 4; ++nf)
#pragma unroll
                        for (int r = 0; r < 4; ++r) {
                            float e = exp2fast(sacc[mf][nf][r] - mnew);
                            sacc[mf][nf][r] = e;
                            rsum += e;
                        }
                    rsum += __shfl_xor(rsum, 16);
                    rsum += __shfl_xor(rsum, 32);
                    lrun[mf] = lrun[mf] * alpha + rsum;
                    float aq[4];
#pragma unroll
                    for (int r = 0; r < 4; ++r) aq[r] = __shfl(alpha, lr * 4 + r);
#pragma unroll
                    for (int n4 = 0; n4 < 4; ++n4)
#pragma unroll
                        for (int r = 0; r < 4; ++r) accO[mf][n4][r] *= aq[r];
                } else {
                    // max unchanged for every query in the wave: alpha == 1 exactly
                    float rsum = 0.0f;
#pragma unroll
                    for (int nf = 0; nf < 4; ++nf)
#pragma unroll
                        for (int r = 0; r < 4; ++r) {
                            float e = exp2fast(sacc[mf][nf][r] - mrun[mf]);
                            sacc[mf][nf][r] = e;
                            rsum += e;
                        }
                    rsum += __shfl_xor(rsum, 16);
                    rsum += __shfl_xor(rsum, 32);
                    lrun[mf] += rsum;
                }
            }
#pragma unroll
            for (int mf = 0; mf < 2; ++mf)
#pragma unroll
                for (int nf = 0; nf < 4; ++nf) {
                    bf16x4 o = { (bf16)sacc[mf][nf][0], (bf16)sacc[mf][nf][1],
                                 (bf16)sacc[mf][nf][2], (bf16)sacc[mf][nf][3] };
                    int wb = ((mf * 16 + lc) * 64 + nf * 16 + lr * 4) * 2;
                    *(bf16x4*)(sPw + (wb ^ swz)) = o;
                }
            asm volatile("s_waitcnt lgkmcnt(0)" ::: "memory");
            bf16x8 pf[2][2];
#pragma unroll
            for (int mf = 0; mf < 2; ++mf)
#pragma unroll
                for (int kk = 0; kk < 2; ++kk) {
                    int rb = ((mf * 16 + lc) * 64 + kk * 32 + lr * 8) * 2;
                    pf[mf][kk] = *(const bf16x8*)(sPw + (rb ^ swz));
                }
            __builtin_amdgcn_s_setprio(1);
#pragma unroll
            for (int n4 = 0; n4 < 4; ++n4) {
                int d = n4 * 16 + lc;
#pragma unroll
                for (int kk = 0; kk < 2; ++kk) {
                    bf16x8 vf = *(const bf16x8*)(vb + d * 128 + ((kk * 64 + lr * 16) ^ swz));
                    accO[0][n4] = mfma16(pf[0][kk], vf, accO[0][n4]);
                    accO[1][n4] = mfma16(pf[1][kk], vf, accO[1][n4]);
                }
            }
            __builtin_amdgcn_s_setprio(0);
        }

        __builtin_amdgcn_s_barrier();
        asm volatile("" ::: "memory");
        if (kt + 2 <= kt_hi_b) STAGE_KV(kt + 2, s);
    }
#undef STAGE_KV

#pragma unroll
    for (int mf = 0; mf < 2; ++mf) {
        float linv = 1.0f / lrun[mf];
        float lq[4];
#pragma unroll
        for (int r = 0; r < 4; ++r) lq[r] = __shfl(linv, lr * 4 + r);
#pragma unroll
        for (int n4 = 0; n4 < 4; ++n4)
#pragma unroll
            for (int r = 0; r < 4; ++r) {
                int s = q0 + mf * 16 + lr * 4 + r;
                int d = n4 * 16 + lc;
                ctx[((size_t)(b * S_LEN + s)) * DIM + h * HDIM + d] = (bf16)(accO[mf][n4][r] * lq[r]);
            }
    }
}

extern "C" void kernel_launch(void* const* d_in, const int* in_sizes, int n_in,
                              void* d_out, int out_size, void* d_ws, size_t ws_size,
                              hipStream_t stream) {
    const float* x    = (const float*)d_in[0];
    const float* cosp = (const float*)d_in[2];
    const float* sinp = (const float*)d_in[3];
    const float* Wq   = (const float*)d_in[4];
    const float* bq   = (const float*)d_in[5];
    const float* Wk   = (const float*)d_in[6];
    const float* Wv   = (const float*)d_in[7];
    const float* bv   = (const float*)d_in[8];
    const float* Wo   = (const float*)d_in[9];
    const float* bo   = (const float*)d_in[10];
    float* out = (float*)d_out;

    char* ws = (char*)d_ws;
    const size_t MB = 1ull << 20;
    bf16* xb   = (bf16*)(ws + 0 * MB);
    bf16* WqT  = (bf16*)(ws + 8 * MB);
    bf16* WkT  = (bf16*)(ws + 10 * MB);
    bf16* WvT  = (bf16*)(ws + 12 * MB);
    bf16* WoT  = (bf16*)(ws + 14 * MB);
    bf16* qT   = (bf16*)(ws + 16 * MB);
    bf16* kT   = (bf16*)(ws + 24 * MB);
    bf16* vT   = (bf16*)(ws + 32 * MB);
    bf16* ctx  = (bf16*)(ws + 40 * MB);
    float4* tab = (float4*)(ws + 48 * MB);   // 4 MB RoPE table

    prep_kernel<<<5632, 256, 0, stream>>>(x, cosp, sinp, Wq, Wk, Wv, Wo, xb, tab, WqT, WkT, WvT, WoT);
    gemm_qkv_kernel<<<dim3(32, 8, 3), 256, 0, stream>>>(xb, WqT, WkT, WvT, bq, bv, tab, qT, kT, vT);
    attn_kernel<<<dim3(16, 32), 256, 0, stream>>>(qT, kT, vT, ctx);
    gemm_out_kernel<<<dim3(32, 16), 128, 0, stream>>>(ctx, WoT, bo, out);
}

// Round 18
// 91.302 us; speedup vs baseline: 1.0246x; 1.0246x over previous
//
#include <hip/hip_runtime.h>
#include <cstdint>
#include <cstddef>

typedef __bf16 bf16;
typedef bf16 bf16x4 __attribute__((ext_vector_type(4)));
typedef bf16 bf16x8 __attribute__((ext_vector_type(8)));
typedef float f32x4 __attribute__((ext_vector_type(4)));

#define S_LEN 2048
#define DIM   1024
#define NHEAD 16
#define HDIM  64

__device__ __forceinline__ f32x4 mfma16(bf16x8 a, bf16x8 b, f32x4 c) {
    return __builtin_amdgcn_mfma_f32_16x16x32_bf16(a, b, c, 0, 0, 0);
}

__device__ __forceinline__ float exp2fast(float x) {
    return __builtin_amdgcn_exp2f(x);   // v_exp_f32: 2^x
}

__device__ __forceinline__ void gload_lds16(const bf16* g, bf16* l) {
    __builtin_amdgcn_global_load_lds(
        (const __attribute__((address_space(1))) unsigned*)g,
        (__attribute__((address_space(3))) unsigned*)l, 16, 0, 0);
}

// ================ prep kernel: x convert + RoPE table + 4x weight transpose (FINAL) ================
__global__ __launch_bounds__(256) void prep_kernel(const float* __restrict__ x,
                                                   const float* __restrict__ cosp,
                                                   const float* __restrict__ sinp,
                                                   const float* __restrict__ Wq, const float* __restrict__ Wk,
                                                   const float* __restrict__ Wv, const float* __restrict__ Wo,
                                                   bf16* __restrict__ xb, float4* __restrict__ tab,
                                                   bf16* __restrict__ WqT, bf16* __restrict__ WkT,
                                                   bf16* __restrict__ WvT, bf16* __restrict__ WoT) {
    __shared__ bf16 tile[64][72];
    int blk = blockIdx.x;
    int t = threadIdx.x;
    if (blk < 4096) {
        int i = blk * 256 + t;
        float4 v = ((const float4*)x)[i];
        bf16x4 o = { (bf16)v.x, (bf16)v.y, (bf16)v.z, (bf16)v.w };
        ((bf16x4*)xb)[i] = o;
    } else if (blk < 4608) {
        int i = (blk - 4096) * 256 + t;       // [0, 131072)
        int bs = i >> 5, hd1 = i & 31;
        size_t cb = (size_t)bs * HDIM + hd1;
        tab[i] = make_float4(cosp[cb], sinp[cb], cosp[cb + 32], sinp[cb + 32]);
    } else {
        int blk2 = blk - 4608;                // [0, 1024)
        int z = blk2 >> 8, rem = blk2 & 255;
        int bx = rem & 15, by = rem >> 4;
        const float* W; bf16* WT;
        if      (z == 0) { W = Wq; WT = WqT; }
        else if (z == 1) { W = Wk; WT = WkT; }
        else if (z == 2) { W = Wv; WT = WvT; }
        else             { W = Wo; WT = WoT; }
        int k0 = bx * 64, n0 = by * 64;
#pragma unroll
        for (int p = 0; p < 4; ++p) {
            int task = p * 256 + t;
            int ki = task >> 4, nj = (task & 15) * 4;
            float4 v = *(const float4*)(W + (size_t)(k0 + ki) * DIM + n0 + nj);
            tile[ki][nj + 0] = (bf16)v.x; tile[ki][nj + 1] = (bf16)v.y;
            tile[ki][nj + 2] = (bf16)v.z; tile[ki][nj + 3] = (bf16)v.w;
        }
        __syncthreads();
#pragma unroll
        for (int p = 0; p < 4; ++p) {
            int task = p * 256 + t;
            int ni = task >> 4, kj = (task & 15) * 4;
            bf16x4 o = { tile[kj + 0][ni], tile[kj + 1][ni], tile[kj + 2][ni], tile[kj + 3][ni] };
            *(bf16x4*)(WT + (size_t)(n0 + ni) * DIM + k0 + kj) = o;
        }
    }
}

// ---------------- 128x128 GEMM main loop, ring-3, counted vmcnt (FINAL) ----------------
__device__ __forceinline__ void stage_tile(const bf16* __restrict__ A, const bf16* __restrict__ BT,
                                           int m0, int n0, int k0,
                                           bf16* sA, bf16* sB, int w, int lane) {
#pragma unroll
    for (int p = 0; p < 2; ++p) {
        int c = p * 256 + w * 64 + lane;
        const bf16* ga = A + (size_t)(m0 + (c >> 2)) * DIM + k0 + (c & 3) * 8;
        gload_lds16(ga, sA + (p * 256 + w * 64) * 8);
        const bf16* gb = BT + (size_t)(n0 + (c >> 2)) * DIM + k0 + (c & 3) * 8;
        gload_lds16(gb, sB + (p * 256 + w * 64) * 8);
    }
}

__device__ __forceinline__ void gemm_main(const bf16* __restrict__ A, const bf16* __restrict__ BT,
                                          int m0, int n0, f32x4 acc[4][4]) {
    __shared__ bf16 sA[3][128 * 32];
    __shared__ bf16 sB[3][128 * 32];
    int t = threadIdx.x;
    int lane = t & 63, w = t >> 6;
    int wr = w >> 1, wc = w & 1;
    int lc = lane & 15, lr = lane >> 4;
    const int NSTEP = DIM / 32;           // 32

    stage_tile(A, BT, m0, n0, 0,  sA[0], sB[0], w, lane);
    stage_tile(A, BT, m0, n0, 32, sA[1], sB[1], w, lane);

    int rs = 0, ss = 2;
    for (int kt = 0; kt < NSTEP; ++kt) {
        if (kt < NSTEP - 1) asm volatile("s_waitcnt vmcnt(4)" ::: "memory");
        else                asm volatile("s_waitcnt vmcnt(0)" ::: "memory");
        __builtin_amdgcn_s_barrier();
        asm volatile("" ::: "memory");
        if (kt < NSTEP - 2)
            stage_tile(A, BT, m0, n0, (kt + 2) * 32, sA[ss], sB[ss], w, lane);

        const bf16* pa = sA[rs] + (wr * 64 + lc) * 32 + lr * 8;
        const bf16* pb = sB[rs] + (wc * 64 + lc) * 32 + lr * 8;
        bf16x8 af[4], bfr[4];
#pragma unroll
        for (int m = 0; m < 4; ++m) af[m] = *(const bf16x8*)(pa + m * 16 * 32);
#pragma unroll
        for (int n = 0; n < 4; ++n) bfr[n] = *(const bf16x8*)(pb + n * 16 * 32);
#pragma unroll
        for (int m = 0; m < 4; ++m)
#pragma unroll
            for (int n = 0; n < 4; ++n)
                acc[m][n] = mfma16(af[m], bfr[n], acc[m][n]);
        rs = (rs == 2) ? 0 : rs + 1;
        ss = (ss == 2) ? 0 : ss + 1;
    }
}

// ---------------- fused QKV GEMM + bias + RoPE (table) + head relayout (FINAL) ----------------
__global__ __launch_bounds__(256, 3) void gemm_qkv_kernel(const bf16* __restrict__ xb,
                                                          const bf16* __restrict__ WqT, const bf16* __restrict__ WkT,
                                                          const bf16* __restrict__ WvT,
                                                          const float* __restrict__ bq, const float* __restrict__ bv,
                                                          const float4* __restrict__ tab,
                                                          bf16* __restrict__ qT, bf16* __restrict__ kT,
                                                          bf16* __restrict__ vT) {
    int z = blockIdx.z;
    const bf16* BT = (z == 0) ? WqT : (z == 1) ? WkT : WvT;
    int m0 = blockIdx.x * 128, n0 = blockIdx.y * 128;
    f32x4 acc[4][4] = {};
    gemm_main(xb, BT, m0, n0, acc);

    int t = threadIdx.x;
    int lane = t & 63, w = t >> 6;
    int wr = w >> 1, wc = w & 1;
    int lc = lane & 15, lr = lane >> 4;
    int row0 = m0 + wr * 64 + lr * 4;       // bs base
    int h = (n0 >> 6) + wc;                  // head

    if (z < 2) {
        bf16* qkT = (z == 0) ? qT : kT;
#pragma unroll
        for (int nf = 0; nf < 2; ++nf) {
            int hd1 = lc + nf * 16;          // 0..31
            int c1i = h * HDIM + hd1;
            float b1 = (z == 0) ? bq[c1i] : 0.0f;
            float b2 = (z == 0) ? bq[c1i + 32] : 0.0f;
#pragma unroll
            for (int mf = 0; mf < 4; ++mf) {
#pragma unroll
                for (int r = 0; r < 4; ++r) {
                    int bs = row0 + mf * 16 + r;
                    float4 cs = tab[bs * 32 + hd1];      // (c1, s1, c2, s2)
                    float v1 = acc[mf][nf][r] + b1;
                    float v2 = acc[mf][nf + 2][r] + b2;
                    int b = bs >> 11, s = bs & (S_LEN - 1);
                    size_t o = ((size_t)(b * NHEAD + h) * S_LEN + s) * HDIM;
                    qkT[o + hd1]      = (bf16)(v1 * cs.x - v2 * cs.y);
                    qkT[o + hd1 + 32] = (bf16)(v2 * cs.z + v1 * cs.w);
                }
            }
        }
    } else {
#pragma unroll
        for (int nf = 0; nf < 4; ++nf) {
            int hd = lc + nf * 16;
            float bvv = bv[h * HDIM + hd];
#pragma unroll
            for (int mf = 0; mf < 4; ++mf) {
                bf16x4 o;
#pragma unroll
                for (int r = 0; r < 4; ++r) o[r] = (bf16)(acc[mf][nf][r] + bvv);
                int bs = row0 + mf * 16;
                int b = bs >> 11, s = bs & (S_LEN - 1);
                *(bf16x4*)(vT + ((size_t)((b * NHEAD + h) * HDIM + hd)) * S_LEN + s) = o;
            }
        }
    }
}

// ---------------- out GEMM: 128x64 tile, 2-wave blocks, ring-3, vmcnt(6) (FINAL) ----------------
__device__ __forceinline__ void stage_out(const bf16* __restrict__ A, const bf16* __restrict__ BT,
                                          int m0, int n0, int k0,
                                          bf16* sA, bf16* sB, int w, int t) {
#pragma unroll
    for (int i = 0; i < 4; ++i) {
        int c = i * 128 + t;
        const bf16* ga = A + (size_t)(m0 + (c >> 2)) * DIM + k0 + (c & 3) * 8;
        gload_lds16(ga, sA + (i * 128 + w * 64) * 8);
    }
#pragma unroll
    for (int i = 0; i < 2; ++i) {
        int c = i * 128 + t;
        const bf16* gb = BT + (size_t)(n0 + (c >> 2)) * DIM + k0 + (c & 3) * 8;
        gload_lds16(gb, sB + (i * 128 + w * 64) * 8);
    }
}

__global__ __launch_bounds__(128, 2) void gemm_out_kernel(const bf16* __restrict__ ctx, const bf16* __restrict__ WoT,
                                                          const float* __restrict__ bo, float* __restrict__ out) {
    __shared__ bf16 sA[3][128 * 32];
    __shared__ bf16 sB[3][64 * 32];
    int bid = blockIdx.x + 32 * blockIdx.y;          // 512 blocks
    int wg  = (bid & 7) * 64 + (bid >> 3);           // XCD-bijective (512 % 8 == 0)
    int bx = wg & 31, by = wg >> 5;
    int m0 = bx * 128, n0 = by * 64;
    int t = threadIdx.x, lane = t & 63, w = t >> 6;
    int lc = lane & 15, lr = lane >> 4;
    const int NSTEP = DIM / 32;

    f32x4 acc[4][4] = {};
    stage_out(ctx, WoT, m0, n0, 0,  sA[0], sB[0], w, t);
    stage_out(ctx, WoT, m0, n0, 32, sA[1], sB[1], w, t);

    int rs = 0, ss = 2;
    for (int kt = 0; kt < NSTEP; ++kt) {
        if (kt < NSTEP - 1) asm volatile("s_waitcnt vmcnt(6)" ::: "memory");
        else                asm volatile("s_waitcnt vmcnt(0)" ::: "memory");
        __builtin_amdgcn_s_barrier();
        asm volatile("" ::: "memory");
        if (kt < NSTEP - 2)
            stage_out(ctx, WoT, m0, n0, (kt + 2) * 32, sA[ss], sB[ss], w, t);

        const bf16* pa = sA[rs] + (w * 64 + lc) * 32 + lr * 8;
        const bf16* pb = sB[rs] + lc * 32 + lr * 8;
        bf16x8 af[4], bfr[4];
#pragma unroll
        for (int m = 0; m < 4; ++m) af[m] = *(const bf16x8*)(pa + m * 16 * 32);
#pragma unroll
        for (int n = 0; n < 4; ++n) bfr[n] = *(const bf16x8*)(pb + n * 16 * 32);
#pragma unroll
        for (int m = 0; m < 4; ++m)
#pragma unroll
            for (int n = 0; n < 4; ++n)
                acc[m][n] = mfma16(af[m], bfr[n], acc[m][n]);
        rs = (rs == 2) ? 0 : rs + 1;
        ss = (ss == 2) ? 0 : ss + 1;
    }

    int row0 = m0 + w * 64 + lr * 4;
#pragma unroll
    for (int nf = 0; nf < 4; ++nf) {
        int col = n0 + lc + nf * 16;
        float bvv = bo[col];
#pragma unroll
        for (int mf = 0; mf < 4; ++mf)
#pragma unroll
            for (int r = 0; r < 4; ++r)
                out[(size_t)(row0 + mf * 16 + r) * DIM + col] = acc[mf][nf][r] + bvv;
    }
}

// ================ flash attention: 16 q-rows/wave, 1024 blocks -> 4 blocks/CU, 4 waves/SIMD ================
// OCCUPANCY CHANGE this round: every previous attn config ran 8 waves/CU (2/SIMD) -- no TLP to
// hide the serial QK->softmax->P-LDS->PV chain, which is why all scheduling levers were null.
// Now: 32bh x 32qb = 1024 blocks, 4 waves each, wave owns 16 q-rows. LDS 40KB -> 4 blocks/CU
// = 16 waves/CU = 4/SIMD (2x latency hiding). Staging cost +25% (5 tiles per 64 q-rows).
__global__ __launch_bounds__(256, 4) void attn_kernel(const bf16* __restrict__ qT, const bf16* __restrict__ kT,
                                                      const bf16* __restrict__ vT, bf16* __restrict__ ctx) {
    int bid = blockIdx.x + 32 * blockIdx.y;      // 1024 blocks
    int xcd = bid & 7, idx = bid >> 3;           // idx 0..127
    int bh = xcd * 4 + (idx >> 5);               // 4 heads per XCD (2MB KV < 4MB L2)
    int qb = idx & 31;                           // 32 q-blocks of 64 rows
    int b = bh >> 4, h = bh & 15;
    int t = threadIdx.x, lane = t & 63, w = t >> 6;
    int lc = lane & 15, lr = lane >> 4;

    __shared__ bf16 sK[2][4096];                 // [slot][key(64)][d(64)] swizzled, 8KB/slot
    __shared__ bf16 sV[2][4096];                 // [slot][d(64)][key(64)] swizzled
    __shared__ bf16 sP[4][1024];                 // per-wave P buffer [q(16)][key(64)]

    const bf16* Qb = qT + (size_t)bh * S_LEN * HDIM;
    const bf16* Kb = kT + (size_t)bh * S_LEN * HDIM;
    const bf16* Vb = vT + (size_t)bh * HDIM * S_LEN;

    const float SCL = 0.125f * 1.44269504089f;   // 1/sqrt(64) * log2(e)
    const int swz = (lc & 7) << 4;               // involution swizzle (bytes)
    char* sPw = (char*)sP[w];

    int q0 = qb * 64 + w * 16;                   // wave's 16 q-rows
    int kt_lo_b = (qb >= 4) ? qb - 4 : 0;        // block tiles [qb-4, qb]
    int kt_hi_b = qb;
    int klo_w = (q0 >= 256) ? (q0 - 256) >> 6 : 0;
    int khi_w = q0 >> 6;

    bf16x8 qf[2];
#pragma unroll
    for (int kk = 0; kk < 2; ++kk)
        qf[kk] = *(const bf16x8*)(Qb + (size_t)(q0 + lc) * HDIM + kk * 32 + lr * 8);

    f32x4 accO[4] = {};
    float mrun = -30000.0f;
    float lrun = 0.0f;

#define STAGE_KV(kt_, s_) {                                                             \
        int kbase_ = (kt_) * 64;                                                        \
        _Pragma("unroll")                                                               \
        for (int p = 0; p < 2; ++p) {                                                   \
            int c = p * 256 + t;                                                        \
            int row = c >> 3, ch = c & 7;                                               \
            int colb = (ch * 16) ^ ((row & 7) << 4);                                    \
            bf16* dst = (bf16*)&sK[s_][0] + (p * 256 + (t & ~63)) * 8;                  \
            gload_lds16(Kb + (size_t)(kbase_ + row) * HDIM + (colb >> 1), dst);         \
            bf16* dsv = (bf16*)&sV[s_][0] + (p * 256 + (t & ~63)) * 8;                  \
            gload_lds16(Vb + (size_t)row * S_LEN + kbase_ + (colb >> 1), dsv);          \
        }                                                                               \
    }

    STAGE_KV(kt_lo_b, 0);
    if (kt_lo_b + 1 <= kt_hi_b) STAGE_KV(kt_lo_b + 1, 1);

    for (int kt = kt_lo_b; kt <= kt_hi_b; ++kt) {
        int s = (kt - kt_lo_b) & 1;
        if (kt < kt_hi_b) asm volatile("s_waitcnt vmcnt(4)" ::: "memory");
        else              asm volatile("s_waitcnt vmcnt(0)" ::: "memory");
        __builtin_amdgcn_s_barrier();
        asm volatile("" ::: "memory");

        if (kt >= klo_w && kt <= khi_w) {
            int kbase = kt * 64;
            const char* kb = (const char*)&sK[s][0];
            const char* vb = (const char*)&sV[s][0];

            f32x4 sacc[4] = {};
            __builtin_amdgcn_s_setprio(1);
#pragma unroll
            for (int nf = 0; nf < 4; ++nf) {
                int key = nf * 16 + lc;
#pragma unroll
                for (int kk = 0; kk < 2; ++kk) {
                    bf16x8 kf = *(const bf16x8*)(kb + key * 128 + ((kk * 64 + lr * 16) ^ swz));
                    sacc[nf] = mfma16(kf, qf[kk], sacc[nf]);
                }
            }
            __builtin_amdgcn_s_setprio(0);
            // mask + scale (log2 domain): lane holds (query q0+lc, key kbase+nf*16+lr*4+r)
            int qi = q0 + lc;
#pragma unroll
            for (int nf = 0; nf < 4; ++nf)
#pragma unroll
                for (int r = 0; r < 4; ++r) {
                    int ki = kbase + nf * 16 + lr * 4 + r;
                    bool keep = (ki <= qi) && (ki >= qi - 256);
                    sacc[nf][r] = keep ? sacc[nf][r] * SCL : -30000.0f;
                }
            // online softmax per query-lane
            {
                float mx = sacc[0][0];
#pragma unroll
                for (int nf = 0; nf < 4; ++nf)
#pragma unroll
                    for (int r = 0; r < 4; ++r) mx = fmaxf(mx, sacc[nf][r]);
                mx = fmaxf(mx, __shfl_xor(mx, 16));
                mx = fmaxf(mx, __shfl_xor(mx, 32));
                float mnew = fmaxf(mrun, mx);
                float alpha = exp2fast(mrun - mnew);
                mrun = mnew;
                float rsum = 0.0f;
#pragma unroll
                for (int nf = 0; nf < 4; ++nf)
#pragma unroll
                    for (int r = 0; r < 4; ++r) {
                        float e = exp2fast(sacc[nf][r] - mnew);
                        sacc[nf][r] = e;
                        rsum += e;
                    }
                rsum += __shfl_xor(rsum, 16);
                rsum += __shfl_xor(rsum, 32);
                lrun = lrun * alpha + rsum;
                float aq[4];
#pragma unroll
                for (int r = 0; r < 4; ++r) aq[r] = __shfl(alpha, lr * 4 + r);
#pragma unroll
                for (int n4 = 0; n4 < 4; ++n4)
#pragma unroll
                    for (int r = 0; r < 4; ++r) accO[n4][r] *= aq[r];
            }
            // P -> per-wave LDS (swizzled): row = query lc (16 rows), cols nf*16+lr*4
#pragma unroll
            for (int nf = 0; nf < 4; ++nf) {
                bf16x4 o = { (bf16)sacc[nf][0], (bf16)sacc[nf][1],
                             (bf16)sacc[nf][2], (bf16)sacc[nf][3] };
                int wb = (lc * 64 + nf * 16 + lr * 4) * 2;
                *(bf16x4*)(sPw + (wb ^ swz)) = o;
            }
            asm volatile("s_waitcnt lgkmcnt(0)" ::: "memory");
            bf16x8 pf[2];
#pragma unroll
            for (int kk = 0; kk < 2; ++kk) {
                int rb = (lc * 64 + kk * 32 + lr * 8) * 2;
                pf[kk] = *(const bf16x8*)(sPw + (rb ^ swz));
            }
            __builtin_amdgcn_s_setprio(1);
#pragma unroll
            for (int n4 = 0; n4 < 4; ++n4) {
                int d = n4 * 16 + lc;
#pragma unroll
                for (int kk = 0; kk < 2; ++kk) {
                    bf16x8 vf = *(const bf16x8*)(vb + d * 128 + ((kk * 64 + lr * 16) ^ swz));
                    accO[n4] = mfma16(pf[kk], vf, accO[n4]);
                }
            }
            __builtin_amdgcn_s_setprio(0);
        }

        __builtin_amdgcn_s_barrier();
        asm volatile("" ::: "memory");
        if (kt + 2 <= kt_hi_b) STAGE_KV(kt + 2, s);
    }
#undef STAGE_KV

    // epilogue: accO[n4][r] -> ctx[b][q0+lr*4+r][h*64 + n4*16+lc]
    {
        float linv = 1.0f / lrun;
        float lq[4];
#pragma unroll
        for (int r = 0; r < 4; ++r) lq[r] = __shfl(linv, lr * 4 + r);
#pragma unroll
        for (int n4 = 0; n4 < 4; ++n4)
#pragma unroll
            for (int r = 0; r < 4; ++r) {
                int s = q0 + lr * 4 + r;
                int d = n4 * 16 + lc;
                ctx[((size_t)(b * S_LEN + s)) * DIM + h * HDIM + d] = (bf16)(accO[n4][r] * lq[r]);
            }
    }
}

extern "C" void kernel_launch(void* const* d_in, const int* in_sizes, int n_in,
                              void* d_out, int out_size, void* d_ws, size_t ws_size,
                              hipStream_t stream) {
    const float* x    = (const float*)d_in[0];
    const float* cosp = (const float*)d_in[2];
    const float* sinp = (const float*)d_in[3];
    const float* Wq   = (const float*)d_in[4];
    const float* bq   = (const float*)d_in[5];
    const float* Wk   = (const float*)d_in[6];
    const float* Wv   = (const float*)d_in[7];
    const float* bv   = (const float*)d_in[8];
    const float* Wo   = (const float*)d_in[9];
    const float* bo   = (const float*)d_in[10];
    float* out = (float*)d_out;

    char* ws = (char*)d_ws;
    const size_t MB = 1ull << 20;
    bf16* xb   = (bf16*)(ws + 0 * MB);
    bf16* WqT  = (bf16*)(ws + 8 * MB);
    bf16* WkT  = (bf16*)(ws + 10 * MB);
    bf16* WvT  = (bf16*)(ws + 12 * MB);
    bf16* WoT  = (bf16*)(ws + 14 * MB);
    bf16* qT   = (bf16*)(ws + 16 * MB);
    bf16* kT   = (bf16*)(ws + 24 * MB);
    bf16* vT   = (bf16*)(ws + 32 * MB);
    bf16* ctx  = (bf16*)(ws + 40 * MB);
    float4* tab = (float4*)(ws + 48 * MB);   // 4 MB RoPE table

    prep_kernel<<<5632, 256, 0, stream>>>(x, cosp, sinp, Wq, Wk, Wv, Wo, xb, tab, WqT, WkT, WvT, WoT);
    gemm_qkv_kernel<<<dim3(32, 8, 3), 256, 0, stream>>>(xb, WqT, WkT, WvT, bq, bv, tab, qT, kT, vT);
    attn_kernel<<<dim3(32, 32), 256, 0, stream>>>(qT, kT, vT, ctx);
    gemm_out_kernel<<<dim3(32, 16), 128, 0, stream>>>(ctx, WoT, bo, out);
}

// Round 19
// 90.869 us; speedup vs baseline: 1.0294x; 1.0048x over previous
//
#include <hip/hip_runtime.h>
#include <cstdint>
#include <cstddef>

typedef __bf16 bf16;
typedef bf16 bf16x4 __attribute__((ext_vector_type(4)));
typedef bf16 bf16x8 __attribute__((ext_vector_type(8)));
typedef float f32x4 __attribute__((ext_vector_type(4)));

#define S_LEN 2048
#define DIM   1024
#define NHEAD 16
#define HDIM  64

__device__ __forceinline__ f32x4 mfma16(bf16x8 a, bf16x8 b, f32x4 c) {
    return __builtin_amdgcn_mfma_f32_16x16x32_bf16(a, b, c, 0, 0, 0);
}

__device__ __forceinline__ float exp2fast(float x) {
    return __builtin_amdgcn_exp2f(x);   // v_exp_f32: 2^x
}

__device__ __forceinline__ void gload_lds16(const bf16* g, bf16* l) {
    __builtin_amdgcn_global_load_lds(
        (const __attribute__((address_space(1))) unsigned*)g,
        (__attribute__((address_space(3))) unsigned*)l, 16, 0, 0);
}

// ================ prep kernel: x convert + RoPE table + 4x weight transpose (FINAL) ================
__global__ __launch_bounds__(256) void prep_kernel(const float* __restrict__ x,
                                                   const float* __restrict__ cosp,
                                                   const float* __restrict__ sinp,
                                                   const float* __restrict__ Wq, const float* __restrict__ Wk,
                                                   const float* __restrict__ Wv, const float* __restrict__ Wo,
                                                   bf16* __restrict__ xb, float4* __restrict__ tab,
                                                   bf16* __restrict__ WqT, bf16* __restrict__ WkT,
                                                   bf16* __restrict__ WvT, bf16* __restrict__ WoT) {
    __shared__ bf16 tile[64][72];
    int blk = blockIdx.x;
    int t = threadIdx.x;
    if (blk < 4096) {
        int i = blk * 256 + t;
        float4 v = ((const float4*)x)[i];
        bf16x4 o = { (bf16)v.x, (bf16)v.y, (bf16)v.z, (bf16)v.w };
        ((bf16x4*)xb)[i] = o;
    } else if (blk < 4608) {
        int i = (blk - 4096) * 256 + t;       // [0, 131072)
        int bs = i >> 5, hd1 = i & 31;
        size_t cb = (size_t)bs * HDIM + hd1;
        tab[i] = make_float4(cosp[cb], sinp[cb], cosp[cb + 32], sinp[cb + 32]);
    } else {
        int blk2 = blk - 4608;                // [0, 1024)
        int z = blk2 >> 8, rem = blk2 & 255;
        int bx = rem & 15, by = rem >> 4;
        const float* W; bf16* WT;
        if      (z == 0) { W = Wq; WT = WqT; }
        else if (z == 1) { W = Wk; WT = WkT; }
        else if (z == 2) { W = Wv; WT = WvT; }
        else             { W = Wo; WT = WoT; }
        int k0 = bx * 64, n0 = by * 64;
#pragma unroll
        for (int p = 0; p < 4; ++p) {
            int task = p * 256 + t;
            int ki = task >> 4, nj = (task & 15) * 4;
            float4 v = *(const float4*)(W + (size_t)(k0 + ki) * DIM + n0 + nj);
            tile[ki][nj + 0] = (bf16)v.x; tile[ki][nj + 1] = (bf16)v.y;
            tile[ki][nj + 2] = (bf16)v.z; tile[ki][nj + 3] = (bf16)v.w;
        }
        __syncthreads();
#pragma unroll
        for (int p = 0; p < 4; ++p) {
            int task = p * 256 + t;
            int ni = task >> 4, kj = (task & 15) * 4;
            bf16x4 o = { tile[kj + 0][ni], tile[kj + 1][ni], tile[kj + 2][ni], tile[kj + 3][ni] };
            *(bf16x4*)(WT + (size_t)(n0 + ni) * DIM + k0 + kj) = o;
        }
    }
}

// ---------------- 128x128 GEMM main loop, ring-3, counted vmcnt + LDS XOR swizzle (NEW) ----------------
// Bank-conflict fix (T2, rule #21 both-sides): fragment reads at row*64B + lr*16B put lanes at bank
// (lc&1)*16 + lr*4 -> 8-way conflict (3.1M conflict cycles/dispatch measured). Involution key
// ((row>>1)&3)<<4 == ((lc>>1)&3)<<4 for every fragment row (row = base + m*16 + lc, 16|base, m*16>>1
// is 0 mod 4) -> each half-wave spreads over 4 bank slots = 2-way (free). Stage pre-swizzles the
// GLOBAL source chunk (gload_lds dest stays linear); reads XOR the same key.
__device__ __forceinline__ void stage_tile(const bf16* __restrict__ A, const bf16* __restrict__ BT,
                                           int m0, int n0, int k0,
                                           bf16* sA, bf16* sB, int w, int lane) {
#pragma unroll
    for (int p = 0; p < 2; ++p) {
        int c = p * 256 + w * 64 + lane;
        int row = c >> 2, ch = c & 3;
        int colb = (ch * 16) ^ (((row >> 1) & 3) << 4);   // byte offset in the 64B k-row
        const bf16* ga = A + (size_t)(m0 + row) * DIM + k0 + (colb >> 1);
        gload_lds16(ga, sA + (p * 256 + w * 64) * 8);
        const bf16* gb = BT + (size_t)(n0 + row) * DIM + k0 + (colb >> 1);
        gload_lds16(gb, sB + (p * 256 + w * 64) * 8);
    }
}

__device__ __forceinline__ void gemm_main(const bf16* __restrict__ A, const bf16* __restrict__ BT,
                                          int m0, int n0, f32x4 acc[4][4]) {
    __shared__ bf16 sA[3][128 * 32];
    __shared__ bf16 sB[3][128 * 32];
    int t = threadIdx.x;
    int lane = t & 63, w = t >> 6;
    int wr = w >> 1, wc = w & 1;
    int lc = lane & 15, lr = lane >> 4;
    const int NSTEP = DIM / 32;           // 32

    stage_tile(A, BT, m0, n0, 0,  sA[0], sB[0], w, lane);
    stage_tile(A, BT, m0, n0, 32, sA[1], sB[1], w, lane);

    const int foff = (lr * 16) ^ (((lc >> 1) & 3) << 4);  // swizzled byte offset within 64B row
    const int abase = (wr * 64 + lc) * 64;                 // byte row base for A frags
    const int bbase = (wc * 64 + lc) * 64;                 // byte row base for B frags

    int rs = 0, ss = 2;
    for (int kt = 0; kt < NSTEP; ++kt) {
        if (kt < NSTEP - 1) asm volatile("s_waitcnt vmcnt(4)" ::: "memory");
        else                asm volatile("s_waitcnt vmcnt(0)" ::: "memory");
        __builtin_amdgcn_s_barrier();
        asm volatile("" ::: "memory");
        if (kt < NSTEP - 2)
            stage_tile(A, BT, m0, n0, (kt + 2) * 32, sA[ss], sB[ss], w, lane);

        const char* pa = (const char*)sA[rs];
        const char* pb = (const char*)sB[rs];
        bf16x8 af[4], bfr[4];
#pragma unroll
        for (int m = 0; m < 4; ++m) af[m] = *(const bf16x8*)(pa + abase + m * 1024 + foff);
#pragma unroll
        for (int n = 0; n < 4; ++n) bfr[n] = *(const bf16x8*)(pb + bbase + n * 1024 + foff);
#pragma unroll
        for (int m = 0; m < 4; ++m)
#pragma unroll
            for (int n = 0; n < 4; ++n)
                acc[m][n] = mfma16(af[m], bfr[n], acc[m][n]);
        rs = (rs == 2) ? 0 : rs + 1;
        ss = (ss == 2) ? 0 : ss + 1;
    }
}

// ---------------- fused QKV GEMM + bias + RoPE (table) + head relayout ----------------
__global__ __launch_bounds__(256, 3) void gemm_qkv_kernel(const bf16* __restrict__ xb,
                                                          const bf16* __restrict__ WqT, const bf16* __restrict__ WkT,
                                                          const bf16* __restrict__ WvT,
                                                          const float* __restrict__ bq, const float* __restrict__ bv,
                                                          const float4* __restrict__ tab,
                                                          bf16* __restrict__ qT, bf16* __restrict__ kT,
                                                          bf16* __restrict__ vT) {
    int z = blockIdx.z;
    const bf16* BT = (z == 0) ? WqT : (z == 1) ? WkT : WvT;
    int m0 = blockIdx.x * 128, n0 = blockIdx.y * 128;
    f32x4 acc[4][4] = {};
    gemm_main(xb, BT, m0, n0, acc);

    int t = threadIdx.x;
    int lane = t & 63, w = t >> 6;
    int wr = w >> 1, wc = w & 1;
    int lc = lane & 15, lr = lane >> 4;
    int row0 = m0 + wr * 64 + lr * 4;       // bs base
    int h = (n0 >> 6) + wc;                  // head

    if (z < 2) {
        bf16* qkT = (z == 0) ? qT : kT;
#pragma unroll
        for (int nf = 0; nf < 2; ++nf) {
            int hd1 = lc + nf * 16;          // 0..31
            int c1i = h * HDIM + hd1;
            float b1 = (z == 0) ? bq[c1i] : 0.0f;
            float b2 = (z == 0) ? bq[c1i + 32] : 0.0f;
#pragma unroll
            for (int mf = 0; mf < 4; ++mf) {
#pragma unroll
                for (int r = 0; r < 4; ++r) {
                    int bs = row0 + mf * 16 + r;
                    float4 cs = tab[bs * 32 + hd1];      // (c1, s1, c2, s2)
                    float v1 = acc[mf][nf][r] + b1;
                    float v2 = acc[mf][nf + 2][r] + b2;
                    int b = bs >> 11, s = bs & (S_LEN - 1);
                    size_t o = ((size_t)(b * NHEAD + h) * S_LEN + s) * HDIM;
                    qkT[o + hd1]      = (bf16)(v1 * cs.x - v2 * cs.y);
                    qkT[o + hd1 + 32] = (bf16)(v2 * cs.z + v1 * cs.w);
                }
            }
        }
    } else {
#pragma unroll
        for (int nf = 0; nf < 4; ++nf) {
            int hd = lc + nf * 16;
            float bvv = bv[h * HDIM + hd];
#pragma unroll
            for (int mf = 0; mf < 4; ++mf) {
                bf16x4 o;
#pragma unroll
                for (int r = 0; r < 4; ++r) o[r] = (bf16)(acc[mf][nf][r] + bvv);
                int bs = row0 + mf * 16;
                int b = bs >> 11, s = bs & (S_LEN - 1);
                *(bf16x4*)(vT + ((size_t)((b * NHEAD + h) * HDIM + hd)) * S_LEN + s) = o;
            }
        }
    }
}

// ---------------- out GEMM: 128x64 tile, 2-wave blocks, ring-3, vmcnt(6) (FINAL, unswizzled) ----------------
__device__ __forceinline__ void stage_out(const bf16* __restrict__ A, const bf16* __restrict__ BT,
                                          int m0, int n0, int k0,
                                          bf16* sA, bf16* sB, int w, int t) {
#pragma unroll
    for (int i = 0; i < 4; ++i) {
        int c = i * 128 + t;
        const bf16* ga = A + (size_t)(m0 + (c >> 2)) * DIM + k0 + (c & 3) * 8;
        gload_lds16(ga, sA + (i * 128 + w * 64) * 8);
    }
#pragma unroll
    for (int i = 0; i < 2; ++i) {
        int c = i * 128 + t;
        const bf16* gb = BT + (size_t)(n0 + (c >> 2)) * DIM + k0 + (c & 3) * 8;
        gload_lds16(gb, sB + (i * 128 + w * 64) * 8);
    }
}

__global__ __launch_bounds__(128, 2) void gemm_out_kernel(const bf16* __restrict__ ctx, const bf16* __restrict__ WoT,
                                                          const float* __restrict__ bo, float* __restrict__ out) {
    __shared__ bf16 sA[3][128 * 32];
    __shared__ bf16 sB[3][64 * 32];
    int bid = blockIdx.x + 32 * blockIdx.y;          // 512 blocks
    int wg  = (bid & 7) * 64 + (bid >> 3);           // XCD-bijective (512 % 8 == 0)
    int bx = wg & 31, by = wg >> 5;
    int m0 = bx * 128, n0 = by * 64;
    int t = threadIdx.x, lane = t & 63, w = t >> 6;
    int lc = lane & 15, lr = lane >> 4;
    const int NSTEP = DIM / 32;

    f32x4 acc[4][4] = {};
    stage_out(ctx, WoT, m0, n0, 0,  sA[0], sB[0], w, t);
    stage_out(ctx, WoT, m0, n0, 32, sA[1], sB[1], w, t);

    int rs = 0, ss = 2;
    for (int kt = 0; kt < NSTEP; ++kt) {
        if (kt < NSTEP - 1) asm volatile("s_waitcnt vmcnt(6)" ::: "memory");
        else                asm volatile("s_waitcnt vmcnt(0)" ::: "memory");
        __builtin_amdgcn_s_barrier();
        asm volatile("" ::: "memory");
        if (kt < NSTEP - 2)
            stage_out(ctx, WoT, m0, n0, (kt + 2) * 32, sA[ss], sB[ss], w, t);

        const bf16* pa = sA[rs] + (w * 64 + lc) * 32 + lr * 8;
        const bf16* pb = sB[rs] + lc * 32 + lr * 8;
        bf16x8 af[4], bfr[4];
#pragma unroll
        for (int m = 0; m < 4; ++m) af[m] = *(const bf16x8*)(pa + m * 16 * 32);
#pragma unroll
        for (int n = 0; n < 4; ++n) bfr[n] = *(const bf16x8*)(pb + n * 16 * 32);
#pragma unroll
        for (int m = 0; m < 4; ++m)
#pragma unroll
            for (int n = 0; n < 4; ++n)
                acc[m][n] = mfma16(af[m], bfr[n], acc[m][n]);
        rs = (rs == 2) ? 0 : rs + 1;
        ss = (ss == 2) ? 0 : ss + 1;
    }

    int row0 = m0 + w * 64 + lr * 4;
#pragma unroll
    for (int nf = 0; nf < 4; ++nf) {
        int col = n0 + lc + nf * 16;
        float bvv = bo[col];
#pragma unroll
        for (int mf = 0; mf < 4; ++mf)
#pragma unroll
            for (int r = 0; r < 4; ++r)
                out[(size_t)(row0 + mf * 16 + r) * DIM + col] = acc[mf][nf][r] + bvv;
    }
}

// ================ flash attention: 16 q-rows/wave, 1024 blocks, 4 waves/SIMD (R18 — FINAL) ================
__global__ __launch_bounds__(256, 4) void attn_kernel(const bf16* __restrict__ qT, const bf16* __restrict__ kT,
                                                      const bf16* __restrict__ vT, bf16* __restrict__ ctx) {
    int bid = blockIdx.x + 32 * blockIdx.y;      // 1024 blocks
    int xcd = bid & 7, idx = bid >> 3;           // idx 0..127
    int bh = xcd * 4 + (idx >> 5);               // 4 heads per XCD (2MB KV < 4MB L2)
    int qb = idx & 31;                           // 32 q-blocks of 64 rows
    int b = bh >> 4, h = bh & 15;
    int t = threadIdx.x, lane = t & 63, w = t >> 6;
    int lc = lane & 15, lr = lane >> 4;

    __shared__ bf16 sK[2][4096];                 // [slot][key(64)][d(64)] swizzled, 8KB/slot
    __shared__ bf16 sV[2][4096];                 // [slot][d(64)][key(64)] swizzled
    __shared__ bf16 sP[4][1024];                 // per-wave P buffer [q(16)][key(64)]

    const bf16* Qb = qT + (size_t)bh * S_LEN * HDIM;
    const bf16* Kb = kT + (size_t)bh * S_LEN * HDIM;
    const bf16* Vb = vT + (size_t)bh * HDIM * S_LEN;

    const float SCL = 0.125f * 1.44269504089f;   // 1/sqrt(64) * log2(e)
    const int swz = (lc & 7) << 4;               // involution swizzle (bytes)
    char* sPw = (char*)sP[w];

    int q0 = qb * 64 + w * 16;                   // wave's 16 q-rows
    int kt_lo_b = (qb >= 4) ? qb - 4 : 0;        // block tiles [qb-4, qb]
    int kt_hi_b = qb;
    int klo_w = (q0 >= 256) ? (q0 - 256) >> 6 : 0;
    int khi_w = q0 >> 6;

    bf16x8 qf[2];
#pragma unroll
    for (int kk = 0; kk < 2; ++kk)
        qf[kk] = *(const bf16x8*)(Qb + (size_t)(q0 + lc) * HDIM + kk * 32 + lr * 8);

    f32x4 accO[4] = {};
    float mrun = -30000.0f;
    float lrun = 0.0f;

#define STAGE_KV(kt_, s_) {                                                             \
        int kbase_ = (kt_) * 64;                                                        \
        _Pragma("unroll")                                                               \
        for (int p = 0; p < 2; ++p) {                                                   \
            int c = p * 256 + t;                                                        \
            int row = c >> 3, ch = c & 7;                                               \
            int colb = (ch * 16) ^ ((row & 7) << 4);                                    \
            bf16* dst = (bf16*)&sK[s_][0] + (p * 256 + (t & ~63)) * 8;                  \
            gload_lds16(Kb + (size_t)(kbase_ + row) * HDIM + (colb >> 1), dst);         \
            bf16* dsv = (bf16*)&sV[s_][0] + (p * 256 + (t & ~63)) * 8;                  \
            gload_lds16(Vb + (size_t)row * S_LEN + kbase_ + (colb >> 1), dsv);          \
        }                                                                               \
    }

    STAGE_KV(kt_lo_b, 0);
    if (kt_lo_b + 1 <= kt_hi_b) STAGE_KV(kt_lo_b + 1, 1);

    for (int kt = kt_lo_b; kt <= kt_hi_b; ++kt) {
        int s = (kt - kt_lo_b) & 1;
        if (kt < kt_hi_b) asm volatile("s_waitcnt vmcnt(4)" ::: "memory");
        else              asm volatile("s_waitcnt vmcnt(0)" ::: "memory");
        __builtin_amdgcn_s_barrier();
        asm volatile("" ::: "memory");

        if (kt >= klo_w && kt <= khi_w) {
            int kbase = kt * 64;
            const char* kb = (const char*)&sK[s][0];
            const char* vb = (const char*)&sV[s][0];

            f32x4 sacc[4] = {};
            __builtin_amdgcn_s_setprio(1);
#pragma unroll
            for (int nf = 0; nf < 4; ++nf) {
                int key = nf * 16 + lc;
#pragma unroll
                for (int kk = 0; kk < 2; ++kk) {
                    bf16x8 kf = *(const bf16x8*)(kb + key * 128 + ((kk * 64 + lr * 16) ^ swz));
                    sacc[nf] = mfma16(kf, qf[kk], sacc[nf]);
                }
            }
            __builtin_amdgcn_s_setprio(0);
            int qi = q0 + lc;
#pragma unroll
            for (int nf = 0; nf < 4; ++nf)
#pragma unroll
                for (int r = 0; r < 4; ++r) {
                    int ki = kbase + nf * 16 + lr * 4 + r;
                    bool keep = (ki <= qi) && (ki >= qi - 256);
                    sacc[nf][r] = keep ? sacc[nf][r] * SCL : -30000.0f;
                }
            {
                float mx = sacc[0][0];
#pragma unroll
                for (int nf = 0; nf < 4; ++nf)
#pragma unroll
                    for (int r = 0; r < 4; ++r) mx = fmaxf(mx, sacc[nf][r]);
                mx = fmaxf(mx, __shfl_xor(mx, 16));
                mx = fmaxf(mx, __shfl_xor(mx, 32));
                float mnew = fmaxf(mrun, mx);
                float alpha = exp2fast(mrun - mnew);
                mrun = mnew;
                float rsum = 0.0f;
#pragma unroll
                for (int nf = 0; nf < 4; ++nf)
#pragma unroll
                    for (int r = 0; r < 4; ++r) {
                        float e = exp2fast(sacc[nf][r] - mnew);
                        sacc[nf][r] = e;
                        rsum += e;
                    }
                rsum += __shfl_xor(rsum, 16);
                rsum += __shfl_xor(rsum, 32);
                lrun = lrun * alpha + rsum;
                float aq[4];
#pragma unroll
                for (int r = 0; r < 4; ++r) aq[r] = __shfl(alpha, lr * 4 + r);
#pragma unroll
                for (int n4 = 0; n4 < 4; ++n4)
#pragma unroll
                    for (int r = 0; r < 4; ++r) accO[n4][r] *= aq[r];
            }
#pragma unroll
            for (int nf = 0; nf < 4; ++nf) {
                bf16x4 o = { (bf16)sacc[nf][0], (bf16)sacc[nf][1],
                             (bf16)sacc[nf][2], (bf16)sacc[nf][3] };
                int wb = (lc * 64 + nf * 16 + lr * 4) * 2;
                *(bf16x4*)(sPw + (wb ^ swz)) = o;
            }
            asm volatile("s_waitcnt lgkmcnt(0)" ::: "memory");
            bf16x8 pf[2];
#pragma unroll
            for (int kk = 0; kk < 2; ++kk) {
                int rb = (lc * 64 + kk * 32 + lr * 8) * 2;
                pf[kk] = *(const bf16x8*)(sPw + (rb ^ swz));
            }
            __builtin_amdgcn_s_setprio(1);
#pragma unroll
            for (int n4 = 0; n4 < 4; ++n4) {
                int d = n4 * 16 + lc;
#pragma unroll
                for (int kk = 0; kk < 2; ++kk) {
                    bf16x8 vf = *(const bf16x8*)(vb + d * 128 + ((kk * 64 + lr * 16) ^ swz));
                    accO[n4] = mfma16(pf[kk], vf, accO[n4]);
                }
            }
            __builtin_amdgcn_s_setprio(0);
        }

        __builtin_amdgcn_s_barrier();
        asm volatile("" ::: "memory");
        if (kt + 2 <= kt_hi_b) STAGE_KV(kt + 2, s);
    }
#undef STAGE_KV

    {
        float linv = 1.0f / lrun;
        float lq[4];
#pragma unroll
        for (int r = 0; r < 4; ++r) lq[r] = __shfl(linv, lr * 4 + r);
#pragma unroll
        for (int n4 = 0; n4 < 4; ++n4)
#pragma unroll
            for (int r = 0; r < 4; ++r) {
                int s = q0 + lr * 4 + r;
                int d = n4 * 16 + lc;
                ctx[((size_t)(b * S_LEN + s)) * DIM + h * HDIM + d] = (bf16)(accO[n4][r] * lq[r]);
            }
    }
}

extern "C" void kernel_launch(void* const* d_in, const int* in_sizes, int n_in,
                              void* d_out, int out_size, void* d_ws, size_t ws_size,
                              hipStream_t stream) {
    const float* x    = (const float*)d_in[0];
    const float* cosp = (const float*)d_in[2];
    const float* sinp = (const float*)d_in[3];
    const float* Wq   = (const float*)d_in[4];
    const float* bq   = (const float*)d_in[5];
    const float* Wk   = (const float*)d_in[6];
    const float* Wv   = (const float*)d_in[7];
    const float* bv   = (const float*)d_in[8];
    const float* Wo   = (const float*)d_in[9];
    const float* bo   = (const float*)d_in[10];
    float* out = (float*)d_out;

    char* ws = (char*)d_ws;
    const size_t MB = 1ull << 20;
    bf16* xb   = (bf16*)(ws + 0 * MB);
    bf16* WqT  = (bf16*)(ws + 8 * MB);
    bf16* WkT  = (bf16*)(ws + 10 * MB);
    bf16* WvT  = (bf16*)(ws + 12 * MB);
    bf16* WoT  = (bf16*)(ws + 14 * MB);
    bf16* qT   = (bf16*)(ws + 16 * MB);
    bf16* kT   = (bf16*)(ws + 24 * MB);
    bf16* vT   = (bf16*)(ws + 32 * MB);
    bf16* ctx  = (bf16*)(ws + 40 * MB);
    float4* tab = (float4*)(ws + 48 * MB);   // 4 MB RoPE table

    prep_kernel<<<5632, 256, 0, stream>>>(x, cosp, sinp, Wq, Wk, Wv, Wo, xb, tab, WqT, WkT, WvT, WoT);
    gemm_qkv_kernel<<<dim3(32, 8, 3), 256, 0, stream>>>(xb, WqT, WkT, WvT, bq, bv, tab, qT, kT, vT);
    attn_kernel<<<dim3(32, 32), 256, 0, stream>>>(qT, kT, vT, ctx);
    gemm_out_kernel<<<dim3(32, 16), 128, 0, stream>>>(ctx, WoT, bo, out);
}

// Round 20
// 90.498 us; speedup vs baseline: 1.0337x; 1.0041x over previous
//
#include <hip/hip_runtime.h>
#include <cstdint>
#include <cstddef>

typedef __bf16 bf16;
typedef bf16 bf16x4 __attribute__((ext_vector_type(4)));
typedef bf16 bf16x8 __attribute__((ext_vector_type(8)));
typedef float f32x4 __attribute__((ext_vector_type(4)));

#define S_LEN 2048
#define DIM   1024
#define NHEAD 16
#define HDIM  64

__device__ __forceinline__ f32x4 mfma16(bf16x8 a, bf16x8 b, f32x4 c) {
    return __builtin_amdgcn_mfma_f32_16x16x32_bf16(a, b, c, 0, 0, 0);
}

__device__ __forceinline__ float exp2fast(float x) {
    return __builtin_amdgcn_exp2f(x);   // v_exp_f32: 2^x
}

__device__ __forceinline__ void gload_lds16(const bf16* g, bf16* l) {
    __builtin_amdgcn_global_load_lds(
        (const __attribute__((address_space(1))) unsigned*)g,
        (__attribute__((address_space(3))) unsigned*)l, 16, 0, 0);
}

// ================ prep kernel: x convert + RoPE table + 4x weight transpose (FINAL) ================
__global__ __launch_bounds__(256) void prep_kernel(const float* __restrict__ x,
                                                   const float* __restrict__ cosp,
                                                   const float* __restrict__ sinp,
                                                   const float* __restrict__ Wq, const float* __restrict__ Wk,
                                                   const float* __restrict__ Wv, const float* __restrict__ Wo,
                                                   bf16* __restrict__ xb, float4* __restrict__ tab,
                                                   bf16* __restrict__ WqT, bf16* __restrict__ WkT,
                                                   bf16* __restrict__ WvT, bf16* __restrict__ WoT) {
    __shared__ bf16 tile[64][72];
    int blk = blockIdx.x;
    int t = threadIdx.x;
    if (blk < 4096) {
        int i = blk * 256 + t;
        float4 v = ((const float4*)x)[i];
        bf16x4 o = { (bf16)v.x, (bf16)v.y, (bf16)v.z, (bf16)v.w };
        ((bf16x4*)xb)[i] = o;
    } else if (blk < 4608) {
        int i = (blk - 4096) * 256 + t;       // [0, 131072)
        int bs = i >> 5, hd1 = i & 31;
        size_t cb = (size_t)bs * HDIM + hd1;
        tab[i] = make_float4(cosp[cb], sinp[cb], cosp[cb + 32], sinp[cb + 32]);
    } else {
        int blk2 = blk - 4608;                // [0, 1024)
        int z = blk2 >> 8, rem = blk2 & 255;
        int bx = rem & 15, by = rem >> 4;
        const float* W; bf16* WT;
        if      (z == 0) { W = Wq; WT = WqT; }
        else if (z == 1) { W = Wk; WT = WkT; }
        else if (z == 2) { W = Wv; WT = WvT; }
        else             { W = Wo; WT = WoT; }
        int k0 = bx * 64, n0 = by * 64;
#pragma unroll
        for (int p = 0; p < 4; ++p) {
            int task = p * 256 + t;
            int ki = task >> 4, nj = (task & 15) * 4;
            float4 v = *(const float4*)(W + (size_t)(k0 + ki) * DIM + n0 + nj);
            tile[ki][nj + 0] = (bf16)v.x; tile[ki][nj + 1] = (bf16)v.y;
            tile[ki][nj + 2] = (bf16)v.z; tile[ki][nj + 3] = (bf16)v.w;
        }
        __syncthreads();
#pragma unroll
        for (int p = 0; p < 4; ++p) {
            int task = p * 256 + t;
            int ni = task >> 4, kj = (task & 15) * 4;
            bf16x4 o = { tile[kj + 0][ni], tile[kj + 1][ni], tile[kj + 2][ni], tile[kj + 3][ni] };
            *(bf16x4*)(WT + (size_t)(n0 + ni) * DIM + k0 + kj) = o;
        }
    }
}

// ---------------- 128x128 GEMM main loop, ring-3, counted vmcnt + LDS XOR swizzle (FINAL) ----------------
__device__ __forceinline__ void stage_tile(const bf16* __restrict__ A, const bf16* __restrict__ BT,
                                           int m0, int n0, int k0,
                                           bf16* sA, bf16* sB, int w, int lane) {
#pragma unroll
    for (int p = 0; p < 2; ++p) {
        int c = p * 256 + w * 64 + lane;
        int row = c >> 2, ch = c & 3;
        int colb = (ch * 16) ^ (((row >> 1) & 3) << 4);   // byte offset in the 64B k-row
        const bf16* ga = A + (size_t)(m0 + row) * DIM + k0 + (colb >> 1);
        gload_lds16(ga, sA + (p * 256 + w * 64) * 8);
        const bf16* gb = BT + (size_t)(n0 + row) * DIM + k0 + (colb >> 1);
        gload_lds16(gb, sB + (p * 256 + w * 64) * 8);
    }
}

__device__ __forceinline__ void gemm_main(const bf16* __restrict__ A, const bf16* __restrict__ BT,
                                          int m0, int n0, f32x4 acc[4][4]) {
    __shared__ bf16 sA[3][128 * 32];
    __shared__ bf16 sB[3][128 * 32];
    int t = threadIdx.x;
    int lane = t & 63, w = t >> 6;
    int wr = w >> 1, wc = w & 1;
    int lc = lane & 15, lr = lane >> 4;
    const int NSTEP = DIM / 32;           // 32

    stage_tile(A, BT, m0, n0, 0,  sA[0], sB[0], w, lane);
    stage_tile(A, BT, m0, n0, 32, sA[1], sB[1], w, lane);

    const int foff = (lr * 16) ^ (((lc >> 1) & 3) << 4);  // swizzled byte offset within 64B row
    const int abase = (wr * 64 + lc) * 64;                 // byte row base for A frags
    const int bbase = (wc * 64 + lc) * 64;                 // byte row base for B frags

    int rs = 0, ss = 2;
    for (int kt = 0; kt < NSTEP; ++kt) {
        if (kt < NSTEP - 1) asm volatile("s_waitcnt vmcnt(4)" ::: "memory");
        else                asm volatile("s_waitcnt vmcnt(0)" ::: "memory");
        __builtin_amdgcn_s_barrier();
        asm volatile("" ::: "memory");
        if (kt < NSTEP - 2)
            stage_tile(A, BT, m0, n0, (kt + 2) * 32, sA[ss], sB[ss], w, lane);

        const char* pa = (const char*)sA[rs];
        const char* pb = (const char*)sB[rs];
        bf16x8 af[4], bfr[4];
#pragma unroll
        for (int m = 0; m < 4; ++m) af[m] = *(const bf16x8*)(pa + abase + m * 1024 + foff);
#pragma unroll
        for (int n = 0; n < 4; ++n) bfr[n] = *(const bf16x8*)(pb + bbase + n * 1024 + foff);
#pragma unroll
        for (int m = 0; m < 4; ++m)
#pragma unroll
            for (int n = 0; n < 4; ++n)
                acc[m][n] = mfma16(af[m], bfr[n], acc[m][n]);
        rs = (rs == 2) ? 0 : rs + 1;
        ss = (ss == 2) ? 0 : ss + 1;
    }
}

// ---------------- fused QKV GEMM + bias + RoPE (table) + head relayout (FINAL) ----------------
__global__ __launch_bounds__(256, 3) void gemm_qkv_kernel(const bf16* __restrict__ xb,
                                                          const bf16* __restrict__ WqT, const bf16* __restrict__ WkT,
                                                          const bf16* __restrict__ WvT,
                                                          const float* __restrict__ bq, const float* __restrict__ bv,
                                                          const float4* __restrict__ tab,
                                                          bf16* __restrict__ qT, bf16* __restrict__ kT,
                                                          bf16* __restrict__ vT) {
    int z = blockIdx.z;
    const bf16* BT = (z == 0) ? WqT : (z == 1) ? WkT : WvT;
    int m0 = blockIdx.x * 128, n0 = blockIdx.y * 128;
    f32x4 acc[4][4] = {};
    gemm_main(xb, BT, m0, n0, acc);

    int t = threadIdx.x;
    int lane = t & 63, w = t >> 6;
    int wr = w >> 1, wc = w & 1;
    int lc = lane & 15, lr = lane >> 4;
    int row0 = m0 + wr * 64 + lr * 4;       // bs base
    int h = (n0 >> 6) + wc;                  // head

    if (z < 2) {
        bf16* qkT = (z == 0) ? qT : kT;
#pragma unroll
        for (int nf = 0; nf < 2; ++nf) {
            int hd1 = lc + nf * 16;          // 0..31
            int c1i = h * HDIM + hd1;
            float b1 = (z == 0) ? bq[c1i] : 0.0f;
            float b2 = (z == 0) ? bq[c1i + 32] : 0.0f;
#pragma unroll
            for (int mf = 0; mf < 4; ++mf) {
#pragma unroll
                for (int r = 0; r < 4; ++r) {
                    int bs = row0 + mf * 16 + r;
                    float4 cs = tab[bs * 32 + hd1];      // (c1, s1, c2, s2)
                    float v1 = acc[mf][nf][r] + b1;
                    float v2 = acc[mf][nf + 2][r] + b2;
                    int b = bs >> 11, s = bs & (S_LEN - 1);
                    size_t o = ((size_t)(b * NHEAD + h) * S_LEN + s) * HDIM;
                    qkT[o + hd1]      = (bf16)(v1 * cs.x - v2 * cs.y);
                    qkT[o + hd1 + 32] = (bf16)(v2 * cs.z + v1 * cs.w);
                }
            }
        }
    } else {
#pragma unroll
        for (int nf = 0; nf < 4; ++nf) {
            int hd = lc + nf * 16;
            float bvv = bv[h * HDIM + hd];
#pragma unroll
            for (int mf = 0; mf < 4; ++mf) {
                bf16x4 o;
#pragma unroll
                for (int r = 0; r < 4; ++r) o[r] = (bf16)(acc[mf][nf][r] + bvv);
                int bs = row0 + mf * 16;
                int b = bs >> 11, s = bs & (S_LEN - 1);
                *(bf16x4*)(vT + ((size_t)((b * NHEAD + h) * HDIM + hd)) * S_LEN + s) = o;
            }
        }
    }
}

// ---------------- out GEMM: 128x64 tile, 2-wave blocks, ring-3, vmcnt(6) + XOR swizzle (NEW) ----------------
// out-gemm runs 1 wave/SIMD (512 blk x 2 waves / 256 CU) -> its 8-way ds_read_b128 bank conflicts
// have NO co-resident waves to hide behind (unlike qkv at 3/SIMD where the same conflicts were
// timing-null, R19). Same validated involution, both sides (rule #21): key ((row>>1)&3)<<4.
__device__ __forceinline__ void stage_out(const bf16* __restrict__ A, const bf16* __restrict__ BT,
                                          int m0, int n0, int k0,
                                          bf16* sA, bf16* sB, int w, int t) {
#pragma unroll
    for (int i = 0; i < 4; ++i) {
        int c = i * 128 + t;
        int row = c >> 2, ch = c & 3;
        int colb = (ch * 16) ^ (((row >> 1) & 3) << 4);
        const bf16* ga = A + (size_t)(m0 + row) * DIM + k0 + (colb >> 1);
        gload_lds16(ga, sA + (i * 128 + w * 64) * 8);
    }
#pragma unroll
    for (int i = 0; i < 2; ++i) {
        int c = i * 128 + t;
        int row = c >> 2, ch = c & 3;
        int colb = (ch * 16) ^ (((row >> 1) & 3) << 4);
        const bf16* gb = BT + (size_t)(n0 + row) * DIM + k0 + (colb >> 1);
        gload_lds16(gb, sB + (i * 128 + w * 64) * 8);
    }
}

__global__ __launch_bounds__(128, 2) void gemm_out_kernel(const bf16* __restrict__ ctx, const bf16* __restrict__ WoT,
                                                          const float* __restrict__ bo, float* __restrict__ out) {
    __shared__ bf16 sA[3][128 * 32];
    __shared__ bf16 sB[3][64 * 32];
    int bid = blockIdx.x + 32 * blockIdx.y;          // 512 blocks
    int wg  = (bid & 7) * 64 + (bid >> 3);           // XCD-bijective (512 % 8 == 0)
    int bx = wg & 31, by = wg >> 5;
    int m0 = bx * 128, n0 = by * 64;
    int t = threadIdx.x, lane = t & 63, w = t >> 6;
    int lc = lane & 15, lr = lane >> 4;
    const int NSTEP = DIM / 32;

    f32x4 acc[4][4] = {};
    stage_out(ctx, WoT, m0, n0, 0,  sA[0], sB[0], w, t);
    stage_out(ctx, WoT, m0, n0, 32, sA[1], sB[1], w, t);

    const int foff = (lr * 16) ^ (((lc >> 1) & 3) << 4);
    const int abase = (w * 64 + lc) * 64;            // byte row base for A frags
    const int bbase = lc * 64;                        // byte row base for B frags

    int rs = 0, ss = 2;
    for (int kt = 0; kt < NSTEP; ++kt) {
        if (kt < NSTEP - 1) asm volatile("s_waitcnt vmcnt(6)" ::: "memory");
        else                asm volatile("s_waitcnt vmcnt(0)" ::: "memory");
        __builtin_amdgcn_s_barrier();
        asm volatile("" ::: "memory");
        if (kt < NSTEP - 2)
            stage_out(ctx, WoT, m0, n0, (kt + 2) * 32, sA[ss], sB[ss], w, t);

        const char* pa = (const char*)sA[rs];
        const char* pb = (const char*)sB[rs];
        bf16x8 af[4], bfr[4];
#pragma unroll
        for (int m = 0; m < 4; ++m) af[m] = *(const bf16x8*)(pa + abase + m * 1024 + foff);
#pragma unroll
        for (int n = 0; n < 4; ++n) bfr[n] = *(const bf16x8*)(pb + bbase + n * 1024 + foff);
#pragma unroll
        for (int m = 0; m < 4; ++m)
#pragma unroll
            for (int n = 0; n < 4; ++n)
                acc[m][n] = mfma16(af[m], bfr[n], acc[m][n]);
        rs = (rs == 2) ? 0 : rs + 1;
        ss = (ss == 2) ? 0 : ss + 1;
    }

    int row0 = m0 + w * 64 + lr * 4;
#pragma unroll
    for (int nf = 0; nf < 4; ++nf) {
        int col = n0 + lc + nf * 16;
        float bvv = bo[col];
#pragma unroll
        for (int mf = 0; mf < 4; ++mf)
#pragma unroll
            for (int r = 0; r < 4; ++r)
                out[(size_t)(row0 + mf * 16 + r) * DIM + col] = acc[mf][nf][r] + bvv;
    }
}

// ================ flash attention: 16 q-rows/wave, 1024 blocks, 4 waves/SIMD (R18 — FINAL) ================
__global__ __launch_bounds__(256, 4) void attn_kernel(const bf16* __restrict__ qT, const bf16* __restrict__ kT,
                                                      const bf16* __restrict__ vT, bf16* __restrict__ ctx) {
    int bid = blockIdx.x + 32 * blockIdx.y;      // 1024 blocks
    int xcd = bid & 7, idx = bid >> 3;           // idx 0..127
    int bh = xcd * 4 + (idx >> 5);               // 4 heads per XCD (2MB KV < 4MB L2)
    int qb = idx & 31;                           // 32 q-blocks of 64 rows
    int b = bh >> 4, h = bh & 15;
    int t = threadIdx.x, lane = t & 63, w = t >> 6;
    int lc = lane & 15, lr = lane >> 4;

    __shared__ bf16 sK[2][4096];                 // [slot][key(64)][d(64)] swizzled, 8KB/slot
    __shared__ bf16 sV[2][4096];                 // [slot][d(64)][key(64)] swizzled
    __shared__ bf16 sP[4][1024];                 // per-wave P buffer [q(16)][key(64)]

    const bf16* Qb = qT + (size_t)bh * S_LEN * HDIM;
    const bf16* Kb = kT + (size_t)bh * S_LEN * HDIM;
    const bf16* Vb = vT + (size_t)bh * HDIM * S_LEN;

    const float SCL = 0.125f * 1.44269504089f;   // 1/sqrt(64) * log2(e)
    const int swz = (lc & 7) << 4;               // involution swizzle (bytes)
    char* sPw = (char*)sP[w];

    int q0 = qb * 64 + w * 16;                   // wave's 16 q-rows
    int kt_lo_b = (qb >= 4) ? qb - 4 : 0;        // block tiles [qb-4, qb]
    int kt_hi_b = qb;
    int klo_w = (q0 >= 256) ? (q0 - 256) >> 6 : 0;
    int khi_w = q0 >> 6;

    bf16x8 qf[2];
#pragma unroll
    for (int kk = 0; kk < 2; ++kk)
        qf[kk] = *(const bf16x8*)(Qb + (size_t)(q0 + lc) * HDIM + kk * 32 + lr * 8);

    f32x4 accO[4] = {};
    float mrun = -30000.0f;
    float lrun = 0.0f;

#define STAGE_KV(kt_, s_) {                                                             \
        int kbase_ = (kt_) * 64;                                                        \
        _Pragma("unroll")                                                               \
        for (int p = 0; p < 2; ++p) {                                                   \
            int c = p * 256 + t;                                                        \
            int row = c >> 3, ch = c & 7;                                               \
            int colb = (ch * 16) ^ ((row & 7) << 4);                                    \
            bf16* dst = (bf16*)&sK[s_][0] + (p * 256 + (t & ~63)) * 8;                  \
            gload_lds16(Kb + (size_t)(kbase_ + row) * HDIM + (colb >> 1), dst);         \
            bf16* dsv = (bf16*)&sV[s_][0] + (p * 256 + (t & ~63)) * 8;                  \
            gload_lds16(Vb + (size_t)row * S_LEN + kbase_ + (colb >> 1), dsv);          \
        }                                                                               \
    }

    STAGE_KV(kt_lo_b, 0);
    if (kt_lo_b + 1 <= kt_hi_b) STAGE_KV(kt_lo_b + 1, 1);

    for (int kt = kt_lo_b; kt <= kt_hi_b; ++kt) {
        int s = (kt - kt_lo_b) & 1;
        if (kt < kt_hi_b) asm volatile("s_waitcnt vmcnt(4)" ::: "memory");
        else              asm volatile("s_waitcnt vmcnt(0)" ::: "memory");
        __builtin_amdgcn_s_barrier();
        asm volatile("" ::: "memory");

        if (kt >= klo_w && kt <= khi_w) {
            int kbase = kt * 64;
            const char* kb = (const char*)&sK[s][0];
            const char* vb = (const char*)&sV[s][0];

            f32x4 sacc[4] = {};
            __builtin_amdgcn_s_setprio(1);
#pragma unroll
            for (int nf = 0; nf < 4; ++nf) {
                int key = nf * 16 + lc;
#pragma unroll
                for (int kk = 0; kk < 2; ++kk) {
                    bf16x8 kf = *(const bf16x8*)(kb + key * 128 + ((kk * 64 + lr * 16) ^ swz));
                    sacc[nf] = mfma16(kf, qf[kk], sacc[nf]);
                }
            }
            __builtin_amdgcn_s_setprio(0);
            int qi = q0 + lc;
#pragma unroll
            for (int nf = 0; nf < 4; ++nf)
#pragma unroll
                for (int r = 0; r < 4; ++r) {
                    int ki = kbase + nf * 16 + lr * 4 + r;
                    bool keep = (ki <= qi) && (ki >= qi - 256);
                    sacc[nf][r] = keep ? sacc[nf][r] * SCL : -30000.0f;
                }
            {
                float mx = sacc[0][0];
#pragma unroll
                for (int nf = 0; nf < 4; ++nf)
#pragma unroll
                    for (int r = 0; r < 4; ++r) mx = fmaxf(mx, sacc[nf][r]);
                mx = fmaxf(mx, __shfl_xor(mx, 16));
                mx = fmaxf(mx, __shfl_xor(mx, 32));
                float mnew = fmaxf(mrun, mx);
                float alpha = exp2fast(mrun - mnew);
                mrun = mnew;
                float rsum = 0.0f;
#pragma unroll
                for (int nf = 0; nf < 4; ++nf)
#pragma unroll
                    for (int r = 0; r < 4; ++r) {
                        float e = exp2fast(sacc[nf][r] - mnew);
                        sacc[nf][r] = e;
                        rsum += e;
                    }
                rsum += __shfl_xor(rsum, 16);
                rsum += __shfl_xor(rsum, 32);
                lrun = lrun * alpha + rsum;
                float aq[4];
#pragma unroll
                for (int r = 0; r < 4; ++r) aq[r] = __shfl(alpha, lr * 4 + r);
#pragma unroll
                for (int n4 = 0; n4 < 4; ++n4)
#pragma unroll
                    for (int r = 0; r < 4; ++r) accO[n4][r] *= aq[r];
            }
#pragma unroll
            for (int nf = 0; nf < 4; ++nf) {
                bf16x4 o = { (bf16)sacc[nf][0], (bf16)sacc[nf][1],
                             (bf16)sacc[nf][2], (bf16)sacc[nf][3] };
                int wb = (lc * 64 + nf * 16 + lr * 4) * 2;
                *(bf16x4*)(sPw + (wb ^ swz)) = o;
            }
            asm volatile("s_waitcnt lgkmcnt(0)" ::: "memory");
            bf16x8 pf[2];
#pragma unroll
            for (int kk = 0; kk < 2; ++kk) {
                int rb = (lc * 64 + kk * 32 + lr * 8) * 2;
                pf[kk] = *(const bf16x8*)(sPw + (rb ^ swz));
            }
            __builtin_amdgcn_s_setprio(1);
#pragma unroll
            for (int n4 = 0; n4 < 4; ++n4) {
                int d = n4 * 16 + lc;
#pragma unroll
                for (int kk = 0; kk < 2; ++kk) {
                    bf16x8 vf = *(const bf16x8*)(vb + d * 128 + ((kk * 64 + lr * 16) ^ swz));
                    accO[n4] = mfma16(pf[kk], vf, accO[n4]);
                }
            }
            __builtin_amdgcn_s_setprio(0);
        }

        __builtin_amdgcn_s_barrier();
        asm volatile("" ::: "memory");
        if (kt + 2 <= kt_hi_b) STAGE_KV(kt + 2, s);
    }
#undef STAGE_KV

    {
        float linv = 1.0f / lrun;
        float lq[4];
#pragma unroll
        for (int r = 0; r < 4; ++r) lq[r] = __shfl(linv, lr * 4 + r);
#pragma unroll
        for (int n4 = 0; n4 < 4; ++n4)
#pragma unroll
            for (int r = 0; r < 4; ++r) {
                int s = q0 + lr * 4 + r;
                int d = n4 * 16 + lc;
                ctx[((size_t)(b * S_LEN + s)) * DIM + h * HDIM + d] = (bf16)(accO[n4][r] * lq[r]);
            }
    }
}

extern "C" void kernel_launch(void* const* d_in, const int* in_sizes, int n_in,
                              void* d_out, int out_size, void* d_ws, size_t ws_size,
                              hipStream_t stream) {
    const float* x    = (const float*)d_in[0];
    const float* cosp = (const float*)d_in[2];
    const float* sinp = (const float*)d_in[3];
    const float* Wq   = (const float*)d_in[4];
    const float* bq   = (const float*)d_in[5];
    const float* Wk   = (const float*)d_in[6];
    const float* Wv   = (const float*)d_in[7];
    const float* bv   = (const float*)d_in[8];
    const float* Wo   = (const float*)d_in[9];
    const float* bo   = (const float*)d_in[10];
    float* out = (float*)d_out;

    char* ws = (char*)d_ws;
    const size_t MB = 1ull << 20;
    bf16* xb   = (bf16*)(ws + 0 * MB);
    bf16* WqT  = (bf16*)(ws + 8 * MB);
    bf16* WkT  = (bf16*)(ws + 10 * MB);
    bf16* WvT  = (bf16*)(ws + 12 * MB);
    bf16* WoT  = (bf16*)(ws + 14 * MB);
    bf16* qT   = (bf16*)(ws + 16 * MB);
    bf16* kT   = (bf16*)(ws + 24 * MB);
    bf16* vT   = (bf16*)(ws + 32 * MB);
    bf16* ctx  = (bf16*)(ws + 40 * MB);
    float4* tab = (float4*)(ws + 48 * MB);   // 4 MB RoPE table

    prep_kernel<<<5632, 256, 0, stream>>>(x, cosp, sinp, Wq, Wk, Wv, Wo, xb, tab, WqT, WkT, WvT, WoT);
    gemm_qkv_kernel<<<dim3(32, 8, 3), 256, 0, stream>>>(xb, WqT, WkT, WvT, bq, bv, tab, qT, kT, vT);
    attn_kernel<<<dim3(32, 32), 256, 0, stream>>>(qT, kT, vT, ctx);
    gemm_out_kernel<<<dim3(32, 16), 128, 0, stream>>>(ctx, WoT, bo, out);
}